// Round 7
// baseline (407.469 us; speedup 1.0000x reference)
//
#include <hip/hip_runtime.h>
#include <hip/hip_bf16.h>

#define C 128
#define RBFD 20
#define NATOMS 50000
#define SCAN_CHUNK 1024
#define SLAB 256          // edges per gather block; 800000 % 256 == 0
#define SS 32             // sub-slab: x-prefetch depth

// ---------------------------------------------------------------------------
// Kernel 1: setup — transpose W1, W2 into [in][out], zero histogram counters,
// zero the accumulator (needed: boundary atomics + atoms with zero edges).
// ---------------------------------------------------------------------------
__global__ __launch_bounds__(256) void setup_kernel(
    const float* __restrict__ W1, const float* __restrict__ W2,
    float* __restrict__ W1T, float* __restrict__ W2T,
    int* __restrict__ count, float4* __restrict__ acc4,
    int n, int acc_quads)
{
    const int t = blockIdx.x * blockDim.x + threadIdx.x;
    const int stride = gridDim.x * blockDim.x;
    if (t < C * C) {
        int k = t / C;   // in-channel
        int c = t % C;   // out-channel
        W1T[t] = W1[c * C + k];
        W2T[t] = W2[c * C + k];
    }
    for (int i = t; i < n; i += stride) count[i] = 0;
    const float4 z = make_float4(0.f, 0.f, 0.f, 0.f);
    for (int i = t; i < acc_quads; i += stride) acc4[i] = z;
}

// ---------------------------------------------------------------------------
// CSR construction: histogram -> hierarchical exclusive scan -> perm fill
// ---------------------------------------------------------------------------
__global__ __launch_bounds__(256) void histogram_kernel(
    const int* __restrict__ idx, int* __restrict__ count, int E)
{
    int e = blockIdx.x * blockDim.x + threadIdx.x;
    if (e < E) atomicAdd(&count[idx[e]], 1);
}

__global__ __launch_bounds__(256) void scan_partials_kernel(
    const int* __restrict__ count, int* __restrict__ partial, int n)
{
    __shared__ int sm[256];
    const int start = blockIdx.x * SCAN_CHUNK;
    int s = 0;
    for (int i = threadIdx.x; i < SCAN_CHUNK; i += 256) {
        int g = start + i;
        if (g < n) s += count[g];
    }
    sm[threadIdx.x] = s;
    __syncthreads();
    for (int off = 128; off > 0; off >>= 1) {
        if (threadIdx.x < off) sm[threadIdx.x] += sm[threadIdx.x + off];
        __syncthreads();
    }
    if (threadIdx.x == 0) partial[blockIdx.x] = sm[0];
}

__global__ void scan_chunkbase_kernel(int* __restrict__ partial,
                                      int* __restrict__ base,
                                      int nchunks, int n)
{
    if (threadIdx.x == 0 && blockIdx.x == 0) {
        int run = 0;
        for (int k = 0; k < nchunks; ++k) {
            int t = partial[k];
            partial[k] = run;
            run += t;
        }
        base[n] = run;
    }
}

__global__ __launch_bounds__(1024) void scan_apply_kernel(
    const int* __restrict__ count, const int* __restrict__ chunk_base,
    int* __restrict__ base, int* __restrict__ cursor, int n)
{
    __shared__ int sm[SCAN_CHUNK];
    const int t = threadIdx.x;
    const int i = blockIdx.x * SCAN_CHUNK + t;
    int v = (i < n) ? count[i] : 0;
    sm[t] = v;
    __syncthreads();
    for (int off = 1; off < SCAN_CHUNK; off <<= 1) {
        int tmp = (t >= off) ? sm[t - off] : 0;
        __syncthreads();
        sm[t] += tmp;
        __syncthreads();
    }
    if (i < n) {
        int excl = sm[t] - v + chunk_base[blockIdx.x];
        base[i] = excl;
        cursor[i] = excl;
    }
}

// also records the owner atom of each perm slot (sequential-read later)
__global__ __launch_bounds__(256) void fill_perm_kernel(
    const int* __restrict__ idx, int* __restrict__ cursor,
    int* __restrict__ perm, int* __restrict__ own, int E)
{
    int e = blockIdx.x * blockDim.x + threadIdx.x;
    if (e < E) {
        int a = idx[e];
        int pos = atomicAdd(&cursor[a], 1);
        perm[pos] = e;
        own[pos] = a;
    }
}

// ---------------------------------------------------------------------------
// Gather kernel v5: slab-parallel segmented reduction with decoupled
// x-prefetch.  One 128-thread block (thread = channel) per 256-edge slab.
// Per 32-edge sub-slab: issue all 32 x loads into registers first (HBM
// latency hidden under filter phase), then 16 groups of 2 edges each
// (10 float4 rbf loads in flight, 40 FMAs), consuming x at the end of each
// group with flush-on-owner-change segmented accumulation.
// ---------------------------------------------------------------------------
__global__ __launch_bounds__(128, 3) void gather_kernel(
    const float* __restrict__ x,       // [E][C]
    const float* __restrict__ rbf,     // [E][RBFD]
    const float* __restrict__ env,     // [E]
    const int*   __restrict__ perm,    // [E]
    const int*   __restrict__ own,     // [E]
    const float* __restrict__ Wrbf,    // [C][RBFD]
    const float* __restrict__ brbf,    // [C]
    float* __restrict__ acc)           // [N][C] (pre-zeroed)
{
    __shared__ int   e_s[SLAB];
    __shared__ float env_s[SLAB];
    __shared__ int   own_s[SLAB];

    const int tid = threadIdx.x;      // 0..127, = channel
    const int p0  = blockIdx.x * SLAB;

    for (int i = tid; i < SLAB; i += 128) {
        const int e = perm[p0 + i];
        e_s[i]   = e;
        env_s[i] = env[e];
        own_s[i] = own[p0 + i];
    }

    float w[RBFD];
#pragma unroll
    for (int r = 0; r < RBFD; ++r) w[r] = Wrbf[tid * RBFD + r];
    const float bias = brbf[tid];

    __syncthreads();

    const int first_own = own_s[0];
    int   cur = first_own;
    float sum = 0.0f;

#define FLUSH()                                                            \
    do {                                                                   \
        if (cur == first_own) unsafeAtomicAdd(&acc[(size_t)cur * C + tid], sum); \
        else                  acc[(size_t)cur * C + tid] = sum;            \
    } while (0)

    for (int s = 0; s < SLAB; s += SS) {
        // ---- Phase A: issue all SS x loads (independent, 1 VGPR each) ----
        float xr[SS];
#pragma unroll
        for (int i = 0; i < SS; ++i)
            xr[i] = x[(size_t)e_s[s + i] * C + tid];

        // ---- Phase B: filter + consume, 2 edges per group ----
#pragma unroll
        for (int j = 0; j < SS; j += 2) {
            const int e0 = e_s[s + j];
            const int e1 = e_s[s + j + 1];
            const float4* q0 = reinterpret_cast<const float4*>(rbf + (size_t)e0 * RBFD);
            const float4* q1 = reinterpret_cast<const float4*>(rbf + (size_t)e1 * RBFD);
            float4 A0 = q0[0], A1 = q0[1], A2 = q0[2], A3 = q0[3], A4 = q0[4];
            float4 B0 = q1[0], B1 = q1[1], B2 = q1[2], B3 = q1[3], B4 = q1[4];

            float f0 = bias, f1 = bias;
            f0 = fmaf(A0.x,w[0],f0);  f0 = fmaf(A0.y,w[1],f0);
            f0 = fmaf(A0.z,w[2],f0);  f0 = fmaf(A0.w,w[3],f0);
            f0 = fmaf(A1.x,w[4],f0);  f0 = fmaf(A1.y,w[5],f0);
            f0 = fmaf(A1.z,w[6],f0);  f0 = fmaf(A1.w,w[7],f0);
            f0 = fmaf(A2.x,w[8],f0);  f0 = fmaf(A2.y,w[9],f0);
            f0 = fmaf(A2.z,w[10],f0); f0 = fmaf(A2.w,w[11],f0);
            f0 = fmaf(A3.x,w[12],f0); f0 = fmaf(A3.y,w[13],f0);
            f0 = fmaf(A3.z,w[14],f0); f0 = fmaf(A3.w,w[15],f0);
            f0 = fmaf(A4.x,w[16],f0); f0 = fmaf(A4.y,w[17],f0);
            f0 = fmaf(A4.z,w[18],f0); f0 = fmaf(A4.w,w[19],f0);

            f1 = fmaf(B0.x,w[0],f1);  f1 = fmaf(B0.y,w[1],f1);
            f1 = fmaf(B0.z,w[2],f1);  f1 = fmaf(B0.w,w[3],f1);
            f1 = fmaf(B1.x,w[4],f1);  f1 = fmaf(B1.y,w[5],f1);
            f1 = fmaf(B1.z,w[6],f1);  f1 = fmaf(B1.w,w[7],f1);
            f1 = fmaf(B2.x,w[8],f1);  f1 = fmaf(B2.y,w[9],f1);
            f1 = fmaf(B2.z,w[10],f1); f1 = fmaf(B2.w,w[11],f1);
            f1 = fmaf(B3.x,w[12],f1); f1 = fmaf(B3.y,w[13],f1);
            f1 = fmaf(B3.z,w[14],f1); f1 = fmaf(B3.w,w[15],f1);
            f1 = fmaf(B4.x,w[16],f1); f1 = fmaf(B4.y,w[17],f1);
            f1 = fmaf(B4.z,w[18],f1); f1 = fmaf(B4.w,w[19],f1);

            const float v0 = f0 * env_s[s + j]     * xr[j];
            const float v1 = f1 * env_s[s + j + 1] * xr[j + 1];

            const int o0 = own_s[s + j];
            const int o1 = own_s[s + j + 1];
            if (o0 != cur) { FLUSH(); sum = 0.0f; cur = o0; }
            sum += v0;
            if (o1 != cur) { FLUSH(); sum = 0.0f; cur = o1; }
            sum += v1;
        }
    }
    // final flush: cur may span into next slab -> atomic
    unsafeAtomicAdd(&acc[(size_t)cur * C + tid], sum);
#undef FLUSH
}

// ---------------------------------------------------------------------------
// Fused MLP head (unchanged).
// ---------------------------------------------------------------------------
__device__ __forceinline__ float silu_f(float v) {
    return v * (1.0f / (1.0f + __expf(-v)));
}

__global__ __launch_bounds__(256) void mlp_head_kernel(
    const float* __restrict__ acc,   // [N][C]
    const float* __restrict__ W1T,   // [C][C]  (k-major)
    const float* __restrict__ b1,    // [C]
    const float* __restrict__ W2T,   // [C][C]
    const float* __restrict__ b2,    // [C]
    const float* __restrict__ W3,    // [1][C]
    const float* __restrict__ b3,    // [1]
    float* __restrict__ out,         // [N]
    int natoms)
{
    __shared__ float As[C][C + 1];

    const int tid = threadIdx.x;
    const int a0  = blockIdx.x * C;
    const int tc  = tid & 15;
    const int ta  = tid >> 4;
    const int abase = ta * 8;
    const int cbase = tc * 8;

    {
        const int sub = tid >> 7;
        const int k   = tid & 127;
        for (int pair = 0; pair < 64; ++pair) {
            const int al = pair * 2 + sub;
            const int a  = a0 + al;
            float v = (a < natoms) ? acc[(size_t)a * C + k] : 0.0f;
            As[k][al] = v;
        }
    }
    __syncthreads();

    float r[8][8];

    // layer 1
#pragma unroll
    for (int i = 0; i < 8; ++i)
#pragma unroll
        for (int j = 0; j < 8; ++j) r[i][j] = 0.0f;

#pragma unroll 2
    for (int k = 0; k < C; ++k) {
        float4 bq0 = *reinterpret_cast<const float4*>(W1T + k * C + cbase);
        float4 bq1 = *reinterpret_cast<const float4*>(W1T + k * C + cbase + 4);
        float bv[8] = {bq0.x, bq0.y, bq0.z, bq0.w, bq1.x, bq1.y, bq1.z, bq1.w};
        float av[8];
#pragma unroll
        for (int i = 0; i < 8; ++i) av[i] = As[k][abase + i];
#pragma unroll
        for (int i = 0; i < 8; ++i)
#pragma unroll
            for (int j = 0; j < 8; ++j) r[i][j] = fmaf(av[i], bv[j], r[i][j]);
    }

    __syncthreads();
    {
        float bb[8];
#pragma unroll
        for (int j = 0; j < 8; ++j) bb[j] = b1[cbase + j];
#pragma unroll
        for (int i = 0; i < 8; ++i)
#pragma unroll
            for (int j = 0; j < 8; ++j)
                As[cbase + j][abase + i] = silu_f(r[i][j] + bb[j]);
    }
    __syncthreads();

    // layer 2
#pragma unroll
    for (int i = 0; i < 8; ++i)
#pragma unroll
        for (int j = 0; j < 8; ++j) r[i][j] = 0.0f;

#pragma unroll 2
    for (int k = 0; k < C; ++k) {
        float4 bq0 = *reinterpret_cast<const float4*>(W2T + k * C + cbase);
        float4 bq1 = *reinterpret_cast<const float4*>(W2T + k * C + cbase + 4);
        float bv[8] = {bq0.x, bq0.y, bq0.z, bq0.w, bq1.x, bq1.y, bq1.z, bq1.w};
        float av[8];
#pragma unroll
        for (int i = 0; i < 8; ++i) av[i] = As[k][abase + i];
#pragma unroll
        for (int i = 0; i < 8; ++i)
#pragma unroll
            for (int j = 0; j < 8; ++j) r[i][j] = fmaf(av[i], bv[j], r[i][j]);
    }

    __syncthreads();

    // final: silu(.. + b2) . W3
    {
        float bb[8], w3v[8];
#pragma unroll
        for (int j = 0; j < 8; ++j) bb[j] = b2[cbase + j];
        float4 wq0 = *reinterpret_cast<const float4*>(W3 + cbase);
        float4 wq1 = *reinterpret_cast<const float4*>(W3 + cbase + 4);
        w3v[0]=wq0.x; w3v[1]=wq0.y; w3v[2]=wq0.z; w3v[3]=wq0.w;
        w3v[4]=wq1.x; w3v[5]=wq1.y; w3v[6]=wq1.z; w3v[7]=wq1.w;

#pragma unroll
        for (int i = 0; i < 8; ++i) {
            float p = 0.0f;
#pragma unroll
            for (int j = 0; j < 8; ++j)
                p = fmaf(silu_f(r[i][j] + bb[j]), w3v[j], p);
            As[abase + i][tc] = p;
        }
    }
    __syncthreads();

    if (tid < C) {
        const int a = a0 + tid;
        if (a < natoms) {
            float s = 0.0f;
#pragma unroll
            for (int t = 0; t < 16; ++t) s += As[tid][t];
            out[a] = s + b3[0];
        }
    }
}

// ---------------------------------------------------------------------------
extern "C" void kernel_launch(void* const* d_in, const int* in_sizes, int n_in,
                              void* d_out, int out_size, void* d_ws, size_t ws_size,
                              hipStream_t stream) {
    const float* x      = (const float*)d_in[0];
    const float* rbf    = (const float*)d_in[1];
    const float* env    = (const float*)d_in[2];
    const int*   idx    = (const int*)  d_in[3];
    const float* Wrbf   = (const float*)d_in[5];
    const float* brbf   = (const float*)d_in[6];
    const float* W1     = (const float*)d_in[7];
    const float* b1     = (const float*)d_in[8];
    const float* W2     = (const float*)d_in[9];
    const float* b2     = (const float*)d_in[10];
    const float* W3     = (const float*)d_in[11];
    const float* b3     = (const float*)d_in[12];
    float*       out    = (float*)d_out;

    const int E = in_sizes[0] / C;        // 800000
    const int N = NATOMS;                 // 50000
    const int nchunks = (N + SCAN_CHUNK - 1) / SCAN_CHUNK;   // 49

    // workspace layout
    float* acc     = (float*)d_ws;                    // N*C
    float* W1T     = acc + (size_t)N * C;             // C*C
    float* W2T     = W1T + C * C;                     // C*C
    int*   count   = (int*)(W2T + C * C);             // N
    int*   base    = count + N;                       // N+1
    int*   cursor  = base + (N + 1);                  // N
    int*   partial = cursor + N;                      // 64
    int*   perm    = partial + 64;                    // E
    int*   own     = perm + E;                        // E

    // setup: transpose weights + zero counters + zero acc
    setup_kernel<<<2048, 256, 0, stream>>>(W1, W2, W1T, W2T, count,
                                           (float4*)acc, N, (N * C) / 4);

    histogram_kernel<<<(E + 255) / 256, 256, 0, stream>>>(idx, count, E);
    scan_partials_kernel<<<nchunks, 256, 0, stream>>>(count, partial, N);
    scan_chunkbase_kernel<<<1, 64, 0, stream>>>(partial, base, nchunks, N);
    scan_apply_kernel<<<nchunks, SCAN_CHUNK, 0, stream>>>(count, partial, base, cursor, N);
    fill_perm_kernel<<<(E + 255) / 256, 256, 0, stream>>>(idx, cursor, perm, own, E);

    // gather: one 128-thread block per 256-edge slab
    gather_kernel<<<E / SLAB, 128, 0, stream>>>(x, rbf, env, perm, own,
                                                Wrbf, brbf, acc);

    const int tiles = (N + C - 1) / C;
    mlp_head_kernel<<<tiles, 256, 0, stream>>>(acc, W1T, b1, W2T, b2, W3, b3, out, N);
}

// Round 9
// 365.875 us; speedup vs baseline: 1.1137x; 1.1137x over previous
//
#include <hip/hip_runtime.h>
#include <hip/hip_bf16.h>

#define C 128
#define RBFD 20
#define NATOMS 50000
#define SCAN_CHUNK 1024
#define SLAB 128          // edges per gather block; 800000 % 128 == 0
#define SS 32             // sub-slab: x-prefetch depth

// ---------------------------------------------------------------------------
// Kernel 1: setup — transpose W1, W2 into [in][out], zero histogram counters,
// zero the accumulator (needed: boundary atomics + atoms with zero edges).
// ---------------------------------------------------------------------------
__global__ __launch_bounds__(256) void setup_kernel(
    const float* __restrict__ W1, const float* __restrict__ W2,
    float* __restrict__ W1T, float* __restrict__ W2T,
    int* __restrict__ count, float4* __restrict__ acc4,
    int n, int acc_quads)
{
    const int t = blockIdx.x * blockDim.x + threadIdx.x;
    const int stride = gridDim.x * blockDim.x;
    if (t < C * C) {
        int k = t / C;   // in-channel
        int c = t % C;   // out-channel
        W1T[t] = W1[c * C + k];
        W2T[t] = W2[c * C + k];
    }
    for (int i = t; i < n; i += stride) count[i] = 0;
    const float4 z = make_float4(0.f, 0.f, 0.f, 0.f);
    for (int i = t; i < acc_quads; i += stride) acc4[i] = z;
}

// ---------------------------------------------------------------------------
// CSR construction: histogram -> hierarchical exclusive scan -> perm fill
// ---------------------------------------------------------------------------
__global__ __launch_bounds__(256) void histogram_kernel(
    const int* __restrict__ idx, int* __restrict__ count, int E)
{
    int e = blockIdx.x * blockDim.x + threadIdx.x;
    if (e < E) atomicAdd(&count[idx[e]], 1);
}

__global__ __launch_bounds__(256) void scan_partials_kernel(
    const int* __restrict__ count, int* __restrict__ partial, int n)
{
    __shared__ int sm[256];
    const int start = blockIdx.x * SCAN_CHUNK;
    int s = 0;
    for (int i = threadIdx.x; i < SCAN_CHUNK; i += 256) {
        int g = start + i;
        if (g < n) s += count[g];
    }
    sm[threadIdx.x] = s;
    __syncthreads();
    for (int off = 128; off > 0; off >>= 1) {
        if (threadIdx.x < off) sm[threadIdx.x] += sm[threadIdx.x + off];
        __syncthreads();
    }
    if (threadIdx.x == 0) partial[blockIdx.x] = sm[0];
}

__global__ void scan_chunkbase_kernel(int* __restrict__ partial,
                                      int* __restrict__ base,
                                      int nchunks, int n)
{
    if (threadIdx.x == 0 && blockIdx.x == 0) {
        int run = 0;
        for (int k = 0; k < nchunks; ++k) {
            int t = partial[k];
            partial[k] = run;
            run += t;
        }
        base[n] = run;
    }
}

__global__ __launch_bounds__(1024) void scan_apply_kernel(
    const int* __restrict__ count, const int* __restrict__ chunk_base,
    int* __restrict__ base, int* __restrict__ cursor, int n)
{
    __shared__ int sm[SCAN_CHUNK];
    const int t = threadIdx.x;
    const int i = blockIdx.x * SCAN_CHUNK + t;
    int v = (i < n) ? count[i] : 0;
    sm[t] = v;
    __syncthreads();
    for (int off = 1; off < SCAN_CHUNK; off <<= 1) {
        int tmp = (t >= off) ? sm[t - off] : 0;
        __syncthreads();
        sm[t] += tmp;
        __syncthreads();
    }
    if (i < n) {
        int excl = sm[t] - v + chunk_base[blockIdx.x];
        base[i] = excl;
        cursor[i] = excl;
    }
}

// also records the owner atom of each perm slot (sequential-read later)
__global__ __launch_bounds__(256) void fill_perm_kernel(
    const int* __restrict__ idx, int* __restrict__ cursor,
    int* __restrict__ perm, int* __restrict__ own, int E)
{
    int e = blockIdx.x * blockDim.x + threadIdx.x;
    if (e < E) {
        int a = idx[e];
        int pos = atomicAdd(&cursor[a], 1);
        perm[pos] = e;
        own[pos] = a;
    }
}

// ---------------------------------------------------------------------------
// Gather kernel v6: slab-parallel segmented reduction, latency-pipelined.
//  * One 128-thread block (thread = channel) per 128-edge slab.
//  * Phase A: all 32 x-row loads of the sub-slab issued, then
//    sched_barrier(0) pins them ABOVE the filter phase.
//  * Phase B: 2-edge groups; rbf float4s for group j+2 loaded into a NAMED
//    struct (SROA -> registers), sched_barrier(0), then group j's 40 FMAs
//    (depth-1 software pipeline, hand-rotated, all compile-time indices).
//  * Segmented flush-on-owner-change: plain store for slab-interior atoms,
//    atomicAdd only at slab boundaries (~2 per block).
// ---------------------------------------------------------------------------
struct R5 { float4 a, b, c, d, e; };

__device__ __forceinline__ R5 load_rbf5(const float* __restrict__ rbf, int eidx) {
    const float4* q = reinterpret_cast<const float4*>(rbf + (size_t)eidx * RBFD);
    R5 r;
    r.a = q[0]; r.b = q[1]; r.c = q[2]; r.d = q[3]; r.e = q[4];
    return r;
}

__device__ __forceinline__ float dot20(const R5& p, const float* __restrict__ w,
                                       float bias) {
    float f = bias;
    f = fmaf(p.a.x, w[0],  f); f = fmaf(p.a.y, w[1],  f);
    f = fmaf(p.a.z, w[2],  f); f = fmaf(p.a.w, w[3],  f);
    f = fmaf(p.b.x, w[4],  f); f = fmaf(p.b.y, w[5],  f);
    f = fmaf(p.b.z, w[6],  f); f = fmaf(p.b.w, w[7],  f);
    f = fmaf(p.c.x, w[8],  f); f = fmaf(p.c.y, w[9],  f);
    f = fmaf(p.c.z, w[10], f); f = fmaf(p.c.w, w[11], f);
    f = fmaf(p.d.x, w[12], f); f = fmaf(p.d.y, w[13], f);
    f = fmaf(p.d.z, w[14], f); f = fmaf(p.d.w, w[15], f);
    f = fmaf(p.e.x, w[16], f); f = fmaf(p.e.y, w[17], f);
    f = fmaf(p.e.z, w[18], f); f = fmaf(p.e.w, w[19], f);
    return f;
}

__global__ __launch_bounds__(128, 2) void gather_kernel(
    const float* __restrict__ x,       // [E][C]
    const float* __restrict__ rbf,     // [E][RBFD]
    const float* __restrict__ env,     // [E]
    const int*   __restrict__ perm,    // [E]
    const int*   __restrict__ own,     // [E]
    const float* __restrict__ Wrbf,    // [C][RBFD]
    const float* __restrict__ brbf,    // [C]
    float* __restrict__ acc)           // [N][C] (pre-zeroed)
{
    __shared__ int   e_s[SLAB];
    __shared__ float env_s[SLAB];
    __shared__ int   own_s[SLAB];

    const int tid = threadIdx.x;      // 0..127, = channel
    const int p0  = blockIdx.x * SLAB;

    {   // SLAB == blockDim.x: one staging pass, fully coalesced perm/own
        const int e = perm[p0 + tid];
        e_s[tid]   = e;
        env_s[tid] = env[e];
        own_s[tid] = own[p0 + tid];
    }

    float w[RBFD];
#pragma unroll
    for (int r = 0; r < RBFD; ++r) w[r] = Wrbf[tid * RBFD + r];
    const float bias = brbf[tid];

    __syncthreads();

    const int first_own = own_s[0];
    int   cur = first_own;
    float sum = 0.0f;

#define FLUSH()                                                                \
    do {                                                                       \
        if (cur == first_own) unsafeAtomicAdd(&acc[(size_t)cur * C + tid], sum); \
        else                  acc[(size_t)cur * C + tid] = sum;                \
    } while (0)

#pragma unroll 1
    for (int s = 0; s < SLAB; s += SS) {
        // ---- Phase A: all SS x-row loads in flight, pinned ----
        float xr[SS];
#pragma unroll
        for (int i = 0; i < SS; ++i)
            xr[i] = x[(size_t)e_s[s + i] * C + tid];
        __builtin_amdgcn_sched_barrier(0);

        // ---- Phase B: depth-1 rbf pipeline over 2-edge groups ----
        R5 Pa = load_rbf5(rbf, e_s[s + 0]);
        R5 Pb = load_rbf5(rbf, e_s[s + 1]);
        __builtin_amdgcn_sched_barrier(0);

#pragma unroll
        for (int j = 0; j < SS; j += 2) {
            R5 Na, Nb;
            if (j + 2 < SS) {
                Na = load_rbf5(rbf, e_s[s + j + 2]);
                Nb = load_rbf5(rbf, e_s[s + j + 3]);
            }
            __builtin_amdgcn_sched_barrier(0);

            const float f0 = dot20(Pa, w, bias);
            const float f1 = dot20(Pb, w, bias);

            const float v0 = f0 * env_s[s + j]     * xr[j];
            const float v1 = f1 * env_s[s + j + 1] * xr[j + 1];

            const int o0 = own_s[s + j];
            const int o1 = own_s[s + j + 1];
            if (o0 != cur) { FLUSH(); sum = 0.0f; cur = o0; }
            sum += v0;
            if (o1 != cur) { FLUSH(); sum = 0.0f; cur = o1; }
            sum += v1;

            // rotate pipeline registers (SSA renames; no copies emitted)
            if (j + 2 < SS) { Pa = Na; Pb = Nb; }
        }
    }
    // final flush: cur may span into next slab -> atomic
    unsafeAtomicAdd(&acc[(size_t)cur * C + tid], sum);
#undef FLUSH
}

// ---------------------------------------------------------------------------
// Fused MLP head (unchanged).
// ---------------------------------------------------------------------------
__device__ __forceinline__ float silu_f(float v) {
    return v * (1.0f / (1.0f + __expf(-v)));
}

__global__ __launch_bounds__(256) void mlp_head_kernel(
    const float* __restrict__ acc,   // [N][C]
    const float* __restrict__ W1T,   // [C][C]  (k-major)
    const float* __restrict__ b1,    // [C]
    const float* __restrict__ W2T,   // [C][C]
    const float* __restrict__ b2,    // [C]
    const float* __restrict__ W3,    // [1][C]
    const float* __restrict__ b3,    // [1]
    float* __restrict__ out,         // [N]
    int natoms)
{
    __shared__ float As[C][C + 1];

    const int tid = threadIdx.x;
    const int a0  = blockIdx.x * C;
    const int tc  = tid & 15;
    const int ta  = tid >> 4;
    const int abase = ta * 8;
    const int cbase = tc * 8;

    {
        const int sub = tid >> 7;
        const int k   = tid & 127;
        for (int pair = 0; pair < 64; ++pair) {
            const int al = pair * 2 + sub;
            const int a  = a0 + al;
            float v = (a < natoms) ? acc[(size_t)a * C + k] : 0.0f;
            As[k][al] = v;
        }
    }
    __syncthreads();

    float r[8][8];

    // layer 1
#pragma unroll
    for (int i = 0; i < 8; ++i)
#pragma unroll
        for (int j = 0; j < 8; ++j) r[i][j] = 0.0f;

#pragma unroll 2
    for (int k = 0; k < C; ++k) {
        float4 bq0 = *reinterpret_cast<const float4*>(W1T + k * C + cbase);
        float4 bq1 = *reinterpret_cast<const float4*>(W1T + k * C + cbase + 4);
        float bv[8] = {bq0.x, bq0.y, bq0.z, bq0.w, bq1.x, bq1.y, bq1.z, bq1.w};
        float av[8];
#pragma unroll
        for (int i = 0; i < 8; ++i) av[i] = As[k][abase + i];
#pragma unroll
        for (int i = 0; i < 8; ++i)
#pragma unroll
            for (int j = 0; j < 8; ++j) r[i][j] = fmaf(av[i], bv[j], r[i][j]);
    }

    __syncthreads();
    {
        float bb[8];
#pragma unroll
        for (int j = 0; j < 8; ++j) bb[j] = b1[cbase + j];
#pragma unroll
        for (int i = 0; i < 8; ++i)
#pragma unroll
            for (int j = 0; j < 8; ++j)
                As[cbase + j][abase + i] = silu_f(r[i][j] + bb[j]);
    }
    __syncthreads();

    // layer 2
#pragma unroll
    for (int i = 0; i < 8; ++i)
#pragma unroll
        for (int j = 0; j < 8; ++j) r[i][j] = 0.0f;

#pragma unroll 2
    for (int k = 0; k < C; ++k) {
        float4 bq0 = *reinterpret_cast<const float4*>(W2T + k * C + cbase);
        float4 bq1 = *reinterpret_cast<const float4*>(W2T + k * C + cbase + 4);
        float bv[8] = {bq0.x, bq0.y, bq0.z, bq0.w, bq1.x, bq1.y, bq1.z, bq1.w};
        float av[8];
#pragma unroll
        for (int i = 0; i < 8; ++i) av[i] = As[k][abase + i];
#pragma unroll
        for (int i = 0; i < 8; ++i)
#pragma unroll
            for (int j = 0; j < 8; ++j) r[i][j] = fmaf(av[i], bv[j], r[i][j]);
    }

    __syncthreads();

    // final: silu(.. + b2) . W3
    {
        float bb[8], w3v[8];
#pragma unroll
        for (int j = 0; j < 8; ++j) bb[j] = b2[cbase + j];
        float4 wq0 = *reinterpret_cast<const float4*>(W3 + cbase);
        float4 wq1 = *reinterpret_cast<const float4*>(W3 + cbase + 4);
        w3v[0]=wq0.x; w3v[1]=wq0.y; w3v[2]=wq0.z; w3v[3]=wq0.w;
        w3v[4]=wq1.x; w3v[5]=wq1.y; w3v[6]=wq1.z; w3v[7]=wq1.w;

#pragma unroll
        for (int i = 0; i < 8; ++i) {
            float p = 0.0f;
#pragma unroll
            for (int j = 0; j < 8; ++j)
                p = fmaf(silu_f(r[i][j] + bb[j]), w3v[j], p);
            As[abase + i][tc] = p;
        }
    }
    __syncthreads();

    if (tid < C) {
        const int a = a0 + tid;
        if (a < natoms) {
            float s = 0.0f;
#pragma unroll
            for (int t = 0; t < 16; ++t) s += As[tid][t];
            out[a] = s + b3[0];
        }
    }
}

// ---------------------------------------------------------------------------
extern "C" void kernel_launch(void* const* d_in, const int* in_sizes, int n_in,
                              void* d_out, int out_size, void* d_ws, size_t ws_size,
                              hipStream_t stream) {
    const float* x      = (const float*)d_in[0];
    const float* rbf    = (const float*)d_in[1];
    const float* env    = (const float*)d_in[2];
    const int*   idx    = (const int*)  d_in[3];
    const float* Wrbf   = (const float*)d_in[5];
    const float* brbf   = (const float*)d_in[6];
    const float* W1     = (const float*)d_in[7];
    const float* b1     = (const float*)d_in[8];
    const float* W2     = (const float*)d_in[9];
    const float* b2     = (const float*)d_in[10];
    const float* W3     = (const float*)d_in[11];
    const float* b3     = (const float*)d_in[12];
    float*       out    = (float*)d_out;

    const int E = in_sizes[0] / C;        // 800000
    const int N = NATOMS;                 // 50000
    const int nchunks = (N + SCAN_CHUNK - 1) / SCAN_CHUNK;   // 49

    // workspace layout
    float* acc     = (float*)d_ws;                    // N*C
    float* W1T     = acc + (size_t)N * C;             // C*C
    float* W2T     = W1T + C * C;                     // C*C
    int*   count   = (int*)(W2T + C * C);             // N
    int*   base    = count + N;                       // N+1
    int*   cursor  = base + (N + 1);                  // N
    int*   partial = cursor + N;                      // 64
    int*   perm    = partial + 64;                    // E
    int*   own     = perm + E;                        // E

    // setup: transpose weights + zero counters + zero acc
    setup_kernel<<<2048, 256, 0, stream>>>(W1, W2, W1T, W2T, count,
                                           (float4*)acc, N, (N * C) / 4);

    histogram_kernel<<<(E + 255) / 256, 256, 0, stream>>>(idx, count, E);
    scan_partials_kernel<<<nchunks, 256, 0, stream>>>(count, partial, N);
    scan_chunkbase_kernel<<<1, 64, 0, stream>>>(partial, base, nchunks, N);
    scan_apply_kernel<<<nchunks, SCAN_CHUNK, 0, stream>>>(count, partial, base, cursor, N);
    fill_perm_kernel<<<(E + 255) / 256, 256, 0, stream>>>(idx, cursor, perm, own, E);

    // gather: one 128-thread block per 128-edge slab
    gather_kernel<<<E / SLAB, 128, 0, stream>>>(x, rbf, env, perm, own,
                                                Wrbf, brbf, acc);

    const int tiles = (N + C - 1) / C;
    mlp_head_kernel<<<tiles, 256, 0, stream>>>(acc, W1T, b1, W2T, b2, W3, b3, out, N);
}

// Round 10
// 329.729 us; speedup vs baseline: 1.2358x; 1.1096x over previous
//
#include <hip/hip_runtime.h>
#include <hip/hip_bf16.h>

#define C 128
#define RBFD 20
#define NATOMS 50000
#define SCAN_CHUNK 1024
#define SLAB 128          // edges per gather block; 800000 % 128 == 0
#define SS 32             // sub-slab size (edges per pipeline stage)
#define NSS (SLAB / SS)   // 4 sub-slabs per slab

// ---------------------------------------------------------------------------
// Kernel 1: setup — transpose W1, W2 into [in][out], zero histogram counters,
// zero the accumulator (needed: boundary atomics + atoms with zero edges).
// ---------------------------------------------------------------------------
__global__ __launch_bounds__(256) void setup_kernel(
    const float* __restrict__ W1, const float* __restrict__ W2,
    float* __restrict__ W1T, float* __restrict__ W2T,
    int* __restrict__ count, float4* __restrict__ acc4,
    int n, int acc_quads)
{
    const int t = blockIdx.x * blockDim.x + threadIdx.x;
    const int stride = gridDim.x * blockDim.x;
    if (t < C * C) {
        int k = t / C;   // in-channel
        int c = t % C;   // out-channel
        W1T[t] = W1[c * C + k];
        W2T[t] = W2[c * C + k];
    }
    for (int i = t; i < n; i += stride) count[i] = 0;
    const float4 z = make_float4(0.f, 0.f, 0.f, 0.f);
    for (int i = t; i < acc_quads; i += stride) acc4[i] = z;
}

// ---------------------------------------------------------------------------
// CSR construction: histogram -> hierarchical exclusive scan -> perm fill
// ---------------------------------------------------------------------------
__global__ __launch_bounds__(256) void histogram_kernel(
    const int* __restrict__ idx, int* __restrict__ count, int E)
{
    int e = blockIdx.x * blockDim.x + threadIdx.x;
    if (e < E) atomicAdd(&count[idx[e]], 1);
}

__global__ __launch_bounds__(256) void scan_partials_kernel(
    const int* __restrict__ count, int* __restrict__ partial, int n)
{
    __shared__ int sm[256];
    const int start = blockIdx.x * SCAN_CHUNK;
    int s = 0;
    for (int i = threadIdx.x; i < SCAN_CHUNK; i += 256) {
        int g = start + i;
        if (g < n) s += count[g];
    }
    sm[threadIdx.x] = s;
    __syncthreads();
    for (int off = 128; off > 0; off >>= 1) {
        if (threadIdx.x < off) sm[threadIdx.x] += sm[threadIdx.x + off];
        __syncthreads();
    }
    if (threadIdx.x == 0) partial[blockIdx.x] = sm[0];
}

__global__ void scan_chunkbase_kernel(int* __restrict__ partial,
                                      int* __restrict__ base,
                                      int nchunks, int n)
{
    if (threadIdx.x == 0 && blockIdx.x == 0) {
        int run = 0;
        for (int k = 0; k < nchunks; ++k) {
            int t = partial[k];
            partial[k] = run;
            run += t;
        }
        base[n] = run;
    }
}

__global__ __launch_bounds__(1024) void scan_apply_kernel(
    const int* __restrict__ count, const int* __restrict__ chunk_base,
    int* __restrict__ base, int* __restrict__ cursor, int n)
{
    __shared__ int sm[SCAN_CHUNK];
    const int t = threadIdx.x;
    const int i = blockIdx.x * SCAN_CHUNK + t;
    int v = (i < n) ? count[i] : 0;
    sm[t] = v;
    __syncthreads();
    for (int off = 1; off < SCAN_CHUNK; off <<= 1) {
        int tmp = (t >= off) ? sm[t - off] : 0;
        __syncthreads();
        sm[t] += tmp;
        __syncthreads();
    }
    if (i < n) {
        int excl = sm[t] - v + chunk_base[blockIdx.x];
        base[i] = excl;
        cursor[i] = excl;
    }
}

// also records the owner atom of each perm slot (sequential-read later)
__global__ __launch_bounds__(256) void fill_perm_kernel(
    const int* __restrict__ idx, int* __restrict__ cursor,
    int* __restrict__ perm, int* __restrict__ own, int E)
{
    int e = blockIdx.x * blockDim.x + threadIdx.x;
    if (e < E) {
        int a = idx[e];
        int pos = atomicAdd(&cursor[a], 1);
        perm[pos] = e;
        own[pos] = a;
    }
}

// ---------------------------------------------------------------------------
// Gather kernel v7: slab-parallel segmented reduction with COOPERATIVE rbf
// staging and full double-buffering.
//  * One 128-thread block (thread = channel) per 128-edge slab.
//  * Per 32-edge sub-slab, the 640 rbf floats are loaded by 128 threads as
//    5 independent scalar loads each (parallel, one latency) and staged to
//    LDS; the filter phase reads them as wave-uniform ds_read_b128
//    broadcasts -> NO global-memory latency inside the compute loop.
//  * x rows double-buffered in registers (xr[2][32], compile-time indexed
//    after full unroll); rbf LDS ping-pong.  Per stage: issue next loads ->
//    sched_barrier(0) -> compute current -> ds_write next -> syncthreads.
//  * Segmented flush-on-owner-change: plain store for slab-interior atoms,
//    atomicAdd only at slab boundaries.
// ---------------------------------------------------------------------------
__global__ __launch_bounds__(128, 2) void gather_kernel(
    const float* __restrict__ x,       // [E][C]
    const float* __restrict__ rbf,     // [E][RBFD]
    const float* __restrict__ env,     // [E]
    const int*   __restrict__ perm,    // [E]
    const int*   __restrict__ own,     // [E]
    const float* __restrict__ Wrbf,    // [C][RBFD]
    const float* __restrict__ brbf,    // [C]
    float* __restrict__ acc)           // [N][C] (pre-zeroed)
{
    __shared__ int   e_s[SLAB];
    __shared__ float env_s[SLAB];
    __shared__ int   own_s[SLAB];
    __shared__ float rbf_s[2][SS][RBFD];   // 2 x 2560 B, rows 16B-aligned

    const int tid = threadIdx.x;      // 0..127, = channel
    const int p0  = blockIdx.x * SLAB;

    {   // SLAB == blockDim.x: one staging pass, fully coalesced perm/own
        const int e = perm[p0 + tid];
        e_s[tid]   = e;
        env_s[tid] = env[e];
        own_s[tid] = own[p0 + tid];
    }

    float w[RBFD];
#pragma unroll
    for (int r = 0; r < RBFD; ++r) w[r] = Wrbf[tid * RBFD + r];
    const float bias = brbf[tid];

    __syncthreads();

    const int first_own = own_s[0];
    int   cur_own = first_own;
    float sum = 0.0f;

#define FLUSH()                                                                \
    do {                                                                       \
        if (cur_own == first_own)                                              \
            unsafeAtomicAdd(&acc[(size_t)cur_own * C + tid], sum);             \
        else acc[(size_t)cur_own * C + tid] = sum;                             \
    } while (0)

    float xr[2][SS];   // x double-buffer (fully unrolled -> registers)
    float st[5];       // rbf staging registers

    // ---- prologue: stage sub-slab 0 ----
#pragma unroll
    for (int p = 0; p < 5; ++p) {
        const int g = p * 128 + tid;            // 0..639
        st[p] = rbf[(size_t)e_s[g / RBFD] * RBFD + (g % RBFD)];
    }
#pragma unroll
    for (int i = 0; i < SS; ++i)
        xr[0][i] = x[(size_t)e_s[i] * C + tid];
    __builtin_amdgcn_sched_barrier(0);
#pragma unroll
    for (int p = 0; p < 5; ++p) {
        const int g = p * 128 + tid;
        rbf_s[0][g / RBFD][g % RBFD] = st[p];
    }
    __syncthreads();

#pragma unroll
    for (int ss = 0; ss < NSS; ++ss) {
        const int sbase = ss * SS;
        const int cur   = ss & 1;

        // ---- issue next sub-slab's loads (rbf -> regs, x -> regs) ----
        if (ss + 1 < NSS) {
#pragma unroll
            for (int p = 0; p < 5; ++p) {
                const int g = p * 128 + tid;
                st[p] = rbf[(size_t)e_s[sbase + SS + g / RBFD] * RBFD + (g % RBFD)];
            }
#pragma unroll
            for (int i = 0; i < SS; ++i)
                xr[cur ^ 1][i] = x[(size_t)e_s[sbase + SS + i] * C + tid];
        }
        __builtin_amdgcn_sched_barrier(0);

        // ---- compute current sub-slab (LDS broadcasts + registers only) ----
#pragma unroll
        for (int j = 0; j < SS; ++j) {
            const float4* q = reinterpret_cast<const float4*>(&rbf_s[cur][j][0]);
            const float4 a = q[0], b = q[1], c = q[2], d = q[3], e4 = q[4];
            float f = bias;
            f = fmaf(a.x,  w[0],  f); f = fmaf(a.y,  w[1],  f);
            f = fmaf(a.z,  w[2],  f); f = fmaf(a.w,  w[3],  f);
            f = fmaf(b.x,  w[4],  f); f = fmaf(b.y,  w[5],  f);
            f = fmaf(b.z,  w[6],  f); f = fmaf(b.w,  w[7],  f);
            f = fmaf(c.x,  w[8],  f); f = fmaf(c.y,  w[9],  f);
            f = fmaf(c.z,  w[10], f); f = fmaf(c.w,  w[11], f);
            f = fmaf(d.x,  w[12], f); f = fmaf(d.y,  w[13], f);
            f = fmaf(d.z,  w[14], f); f = fmaf(d.w,  w[15], f);
            f = fmaf(e4.x, w[16], f); f = fmaf(e4.y, w[17], f);
            f = fmaf(e4.z, w[18], f); f = fmaf(e4.w, w[19], f);

            const float v = f * env_s[sbase + j] * xr[cur][j];
            const int   o = own_s[sbase + j];
            if (o != cur_own) { FLUSH(); sum = 0.0f; cur_own = o; }
            sum += v;
        }

        // ---- write staged rbf to the other LDS buffer ----
        if (ss + 1 < NSS) {
#pragma unroll
            for (int p = 0; p < 5; ++p) {
                const int g = p * 128 + tid;
                rbf_s[cur ^ 1][g / RBFD][g % RBFD] = st[p];
            }
        }
        __syncthreads();
    }
    // final flush: cur_own may span into next slab -> atomic
    unsafeAtomicAdd(&acc[(size_t)cur_own * C + tid], sum);
#undef FLUSH
}

// ---------------------------------------------------------------------------
// Fused MLP head (unchanged).
// ---------------------------------------------------------------------------
__device__ __forceinline__ float silu_f(float v) {
    return v * (1.0f / (1.0f + __expf(-v)));
}

__global__ __launch_bounds__(256) void mlp_head_kernel(
    const float* __restrict__ acc,   // [N][C]
    const float* __restrict__ W1T,   // [C][C]  (k-major)
    const float* __restrict__ b1,    // [C]
    const float* __restrict__ W2T,   // [C][C]
    const float* __restrict__ b2,    // [C]
    const float* __restrict__ W3,    // [1][C]
    const float* __restrict__ b3,    // [1]
    float* __restrict__ out,         // [N]
    int natoms)
{
    __shared__ float As[C][C + 1];

    const int tid = threadIdx.x;
    const int a0  = blockIdx.x * C;
    const int tc  = tid & 15;
    const int ta  = tid >> 4;
    const int abase = ta * 8;
    const int cbase = tc * 8;

    {
        const int sub = tid >> 7;
        const int k   = tid & 127;
        for (int pair = 0; pair < 64; ++pair) {
            const int al = pair * 2 + sub;
            const int a  = a0 + al;
            float v = (a < natoms) ? acc[(size_t)a * C + k] : 0.0f;
            As[k][al] = v;
        }
    }
    __syncthreads();

    float r[8][8];

    // layer 1
#pragma unroll
    for (int i = 0; i < 8; ++i)
#pragma unroll
        for (int j = 0; j < 8; ++j) r[i][j] = 0.0f;

#pragma unroll 2
    for (int k = 0; k < C; ++k) {
        float4 bq0 = *reinterpret_cast<const float4*>(W1T + k * C + cbase);
        float4 bq1 = *reinterpret_cast<const float4*>(W1T + k * C + cbase + 4);
        float bv[8] = {bq0.x, bq0.y, bq0.z, bq0.w, bq1.x, bq1.y, bq1.z, bq1.w};
        float av[8];
#pragma unroll
        for (int i = 0; i < 8; ++i) av[i] = As[k][abase + i];
#pragma unroll
        for (int i = 0; i < 8; ++i)
#pragma unroll
            for (int j = 0; j < 8; ++j) r[i][j] = fmaf(av[i], bv[j], r[i][j]);
    }

    __syncthreads();
    {
        float bb[8];
#pragma unroll
        for (int j = 0; j < 8; ++j) bb[j] = b1[cbase + j];
#pragma unroll
        for (int i = 0; i < 8; ++i)
#pragma unroll
            for (int j = 0; j < 8; ++j)
                As[cbase + j][abase + i] = silu_f(r[i][j] + bb[j]);
    }
    __syncthreads();

    // layer 2
#pragma unroll
    for (int i = 0; i < 8; ++i)
#pragma unroll
        for (int j = 0; j < 8; ++j) r[i][j] = 0.0f;

#pragma unroll 2
    for (int k = 0; k < C; ++k) {
        float4 bq0 = *reinterpret_cast<const float4*>(W2T + k * C + cbase);
        float4 bq1 = *reinterpret_cast<const float4*>(W2T + k * C + cbase + 4);
        float bv[8] = {bq0.x, bq0.y, bq0.z, bq0.w, bq1.x, bq1.y, bq1.z, bq1.w};
        float av[8];
#pragma unroll
        for (int i = 0; i < 8; ++i) av[i] = As[k][abase + i];
#pragma unroll
        for (int i = 0; i < 8; ++i)
#pragma unroll
            for (int j = 0; j < 8; ++j) r[i][j] = fmaf(av[i], bv[j], r[i][j]);
    }

    __syncthreads();

    // final: silu(.. + b2) . W3
    {
        float bb[8], w3v[8];
#pragma unroll
        for (int j = 0; j < 8; ++j) bb[j] = b2[cbase + j];
        float4 wq0 = *reinterpret_cast<const float4*>(W3 + cbase);
        float4 wq1 = *reinterpret_cast<const float4*>(W3 + cbase + 4);
        w3v[0]=wq0.x; w3v[1]=wq0.y; w3v[2]=wq0.z; w3v[3]=wq0.w;
        w3v[4]=wq1.x; w3v[5]=wq1.y; w3v[6]=wq1.z; w3v[7]=wq1.w;

#pragma unroll
        for (int i = 0; i < 8; ++i) {
            float p = 0.0f;
#pragma unroll
            for (int j = 0; j < 8; ++j)
                p = fmaf(silu_f(r[i][j] + bb[j]), w3v[j], p);
            As[abase + i][tc] = p;
        }
    }
    __syncthreads();

    if (tid < C) {
        const int a = a0 + tid;
        if (a < natoms) {
            float s = 0.0f;
#pragma unroll
            for (int t = 0; t < 16; ++t) s += As[tid][t];
            out[a] = s + b3[0];
        }
    }
}

// ---------------------------------------------------------------------------
extern "C" void kernel_launch(void* const* d_in, const int* in_sizes, int n_in,
                              void* d_out, int out_size, void* d_ws, size_t ws_size,
                              hipStream_t stream) {
    const float* x      = (const float*)d_in[0];
    const float* rbf    = (const float*)d_in[1];
    const float* env    = (const float*)d_in[2];
    const int*   idx    = (const int*)  d_in[3];
    const float* Wrbf   = (const float*)d_in[5];
    const float* brbf   = (const float*)d_in[6];
    const float* W1     = (const float*)d_in[7];
    const float* b1     = (const float*)d_in[8];
    const float* W2     = (const float*)d_in[9];
    const float* b2     = (const float*)d_in[10];
    const float* W3     = (const float*)d_in[11];
    const float* b3     = (const float*)d_in[12];
    float*       out    = (float*)d_out;

    const int E = in_sizes[0] / C;        // 800000
    const int N = NATOMS;                 // 50000
    const int nchunks = (N + SCAN_CHUNK - 1) / SCAN_CHUNK;   // 49

    // workspace layout
    float* acc     = (float*)d_ws;                    // N*C
    float* W1T     = acc + (size_t)N * C;             // C*C
    float* W2T     = W1T + C * C;                     // C*C
    int*   count   = (int*)(W2T + C * C);             // N
    int*   base    = count + N;                       // N+1
    int*   cursor  = base + (N + 1);                  // N
    int*   partial = cursor + N;                      // 64
    int*   perm    = partial + 64;                    // E
    int*   own     = perm + E;                        // E

    // setup: transpose weights + zero counters + zero acc
    setup_kernel<<<2048, 256, 0, stream>>>(W1, W2, W1T, W2T, count,
                                           (float4*)acc, N, (N * C) / 4);

    histogram_kernel<<<(E + 255) / 256, 256, 0, stream>>>(idx, count, E);
    scan_partials_kernel<<<nchunks, 256, 0, stream>>>(count, partial, N);
    scan_chunkbase_kernel<<<1, 64, 0, stream>>>(partial, base, nchunks, N);
    scan_apply_kernel<<<nchunks, SCAN_CHUNK, 0, stream>>>(count, partial, base, cursor, N);
    fill_perm_kernel<<<(E + 255) / 256, 256, 0, stream>>>(idx, cursor, perm, own, E);

    // gather: one 128-thread block per 128-edge slab
    gather_kernel<<<E / SLAB, 128, 0, stream>>>(x, rbf, env, perm, own,
                                                Wrbf, brbf, acc);

    const int tiles = (N + C - 1) / C;
    mlp_head_kernel<<<tiles, 256, 0, stream>>>(acc, W1T, b1, W2T, b2, W3, b3, out, N);
}